// Round 1
// baseline (1026.396 us; speedup 1.0000x reference)
//
#include <hip/hip_runtime.h>
#include <math.h>

// TreeLSTM, B=8, L=4096, D=300, H=128, 12 levels.
// fp32 baseline. Layouts:
//   Level buffers: h,c compacted [M_k,128]; children of row r are rows 2r,2r+1,
//   so the REDUCE GEMM input row is hprev_flat[r*256 .. r*256+255].
//   Wcat[256][640] gate-interleaved: Wcat[k][h*5+g] = (k<128?W_l:W_r)[k%128][g*128+h]
//   -> each thread's 5 consecutive output cols = the 5 gates of one h-index.

#define KC 16
#define BM 64
#define AT_STRIDE 68   // 64 + 4: keeps 16B alignment of each k-row, breaks bank aliasing

__device__ __forceinline__ float sigf(float x) { return 1.0f / (1.0f + __expf(-x)); }

// ---------------- reorder W_l,W_r,b -> Wcat, bcat ----------------
__global__ __launch_bounds__(256) void reorder_kernel(
    const float* __restrict__ W_l, const float* __restrict__ W_r,
    const float* __restrict__ b, float* __restrict__ Wcat, float* __restrict__ bcat)
{
    int idx = blockIdx.x * 256 + threadIdx.x;   // exactly 256*640 threads
    int k = idx / 640;
    int j = idx - k * 640;
    int h = j / 5;
    int g = j - h * 5;
    int src = g * 128 + h;
    float v = (k < 128) ? W_l[k * 640 + src] : W_r[(k - 128) * 640 + src];
    Wcat[idx] = v;
    if (idx < 640) bcat[idx] = b[src];
}

// ---------------- leaf: [32768,300] @ [300,256] + b_leaf -> hA,cA ----------------
__global__ __launch_bounds__(256) void leaf_kernel(
    const float* __restrict__ x, const float* __restrict__ Wleaf,
    const float* __restrict__ bleaf, float* __restrict__ hA, float* __restrict__ cA)
{
    __shared__ float At[KC][AT_STRIDE];
    __shared__ float Bs[KC][128];
    const int tid = threadIdx.x;
    const int r0 = blockIdx.x * BM;
    const int j0 = blockIdx.y * 128;          // 0 -> h half, 128 -> c half
    const int rg = tid >> 5;                  // 0..7  (8 rows each)
    const int cg = tid & 31;                  // 0..31 (4 cols each)

    float binit[4];
    #pragma unroll
    for (int q = 0; q < 4; ++q) binit[q] = bleaf[j0 + cg * 4 + q];
    float acc[8][4];
    #pragma unroll
    for (int r = 0; r < 8; ++r)
        #pragma unroll
        for (int q = 0; q < 4; ++q) acc[r][q] = binit[q];

    for (int k0 = 0; k0 < 304; k0 += KC) {    // 300 padded to 19*16
        #pragma unroll
        for (int i = tid; i < BM * KC; i += 256) {
            int m = i >> 4, kk = i & 15;
            int kg = k0 + kk;
            At[kk][m] = (kg < 300) ? x[(size_t)(r0 + m) * 300 + kg] : 0.0f;
        }
        #pragma unroll
        for (int i = tid; i < KC * 128; i += 256) {
            int kk = i >> 7, c = i & 127;
            int kg = k0 + kk;
            Bs[kk][c] = (kg < 300) ? Wleaf[(size_t)kg * 256 + j0 + c] : 0.0f;
        }
        __syncthreads();
        #pragma unroll
        for (int kk = 0; kk < KC; ++kk) {
            float a[8], bv[4];
            #pragma unroll
            for (int r = 0; r < 8; ++r) a[r] = At[kk][rg * 8 + r];
            #pragma unroll
            for (int q = 0; q < 4; ++q) bv[q] = Bs[kk][cg * 4 + q];
            #pragma unroll
            for (int r = 0; r < 8; ++r)
                #pragma unroll
                for (int q = 0; q < 4; ++q) acc[r][q] += a[r] * bv[q];
        }
        __syncthreads();
    }
    float* dst = (j0 == 0) ? hA : cA;
    #pragma unroll
    for (int r = 0; r < 8; ++r) {
        int row = r0 + rg * 8 + r;            // 32768 % 64 == 0: no guard
        #pragma unroll
        for (int q = 0; q < 4; ++q)
            dst[(size_t)row * 128 + cg * 4 + q] = acc[r][q];
    }
}

// ---------------- one tree level: gates GEMM + LSTM epilogue ----------------
__global__ __launch_bounds__(256) void level_kernel(
    const float* __restrict__ hprev, const float* __restrict__ cprev,
    float* __restrict__ hout, float* __restrict__ cout,
    const float* __restrict__ Wcat, const float* __restrict__ bcat,
    int M, float* __restrict__ out_final)
{
    __shared__ float At[KC][AT_STRIDE];
    __shared__ float Bs[KC][160];
    const int tid = threadIdx.x;
    const int r0 = blockIdx.x * BM;
    const int j0 = blockIdx.y * 160;          // 4 col-blocks of 160 = 32 h-indices
    const int rg = tid >> 5, cg = tid & 31;
    const int hidx = blockIdx.y * 32 + cg;

    float binit[5];
    #pragma unroll
    for (int g = 0; g < 5; ++g) binit[g] = bcat[hidx * 5 + g];
    float acc[8][5];
    #pragma unroll
    for (int r = 0; r < 8; ++r)
        #pragma unroll
        for (int g = 0; g < 5; ++g) acc[r][g] = binit[g];

    for (int k0 = 0; k0 < 256; k0 += KC) {
        #pragma unroll
        for (int i = tid; i < BM * KC; i += 256) {
            int m = i >> 4, kk = i & 15;
            At[kk][m] = hprev[(size_t)(r0 + m) * 256 + k0 + kk];  // padded rows read stale-but-valid floats
        }
        #pragma unroll
        for (int i = tid; i < KC * 160; i += 256) {
            int kk = i / 160, c = i - kk * 160;
            Bs[kk][c] = Wcat[(size_t)(k0 + kk) * 640 + j0 + c];
        }
        __syncthreads();
        #pragma unroll
        for (int kk = 0; kk < KC; ++kk) {
            float a[8], bv[5];
            #pragma unroll
            for (int r = 0; r < 8; ++r) a[r] = At[kk][rg * 8 + r];
            #pragma unroll
            for (int g = 0; g < 5; ++g) bv[g] = Bs[kk][cg * 5 + g];
            #pragma unroll
            for (int r = 0; r < 8; ++r)
                #pragma unroll
                for (int g = 0; g < 5; ++g) acc[r][g] += a[r] * bv[g];
        }
        __syncthreads();
    }
    #pragma unroll
    for (int r = 0; r < 8; ++r) {
        int row = r0 + rg * 8 + r;
        if (row < M) {
            float gi = acc[r][0], gfl = acc[r][1], gfr = acc[r][2];
            float go = acc[r][3], gg = acc[r][4];
            float cl = cprev[(size_t)(2 * row) * 128 + hidx];
            float cr = cprev[(size_t)(2 * row + 1) * 128 + hidx];
            float cn = sigf(gfl) * cl + sigf(gfr) * cr + sigf(gi) * tanhf(gg);
            float hn = sigf(go) * tanhf(cn);
            if (out_final) {
                out_final[(size_t)row * 128 + hidx] = hn;   // last level: rows == batch
            } else {
                hout[(size_t)row * 128 + hidx] = hn;
                cout[(size_t)row * 128 + hidx] = cn;
            }
        }
    }
}

extern "C" void kernel_launch(void* const* d_in, const int* in_sizes, int n_in,
                              void* d_out, int out_size, void* d_ws, size_t ws_size,
                              hipStream_t stream)
{
    const float* x      = (const float*)d_in[0];
    const float* W_leaf = (const float*)d_in[1];
    const float* b_leaf = (const float*)d_in[2];
    const float* W_l    = (const float*)d_in[3];
    const float* W_r    = (const float*)d_in[4];
    const float* b      = (const float*)d_in[5];
    float* out = (float*)d_out;

    // workspace layout (floats): hA[32768*128] cA[32768*128] hB[16384*128] cB[16384*128]
    //                            Wcat[256*640] bcat[640]   -> ~51 MB total
    float* hA   = (float*)d_ws;
    float* cA   = hA + (size_t)32768 * 128;
    float* hB   = cA + (size_t)32768 * 128;
    float* cB   = hB + (size_t)16384 * 128;
    float* Wcat = cB + (size_t)16384 * 128;
    float* bcat = Wcat + 256 * 640;

    reorder_kernel<<<dim3(640), dim3(256), 0, stream>>>(W_l, W_r, b, Wcat, bcat);
    leaf_kernel<<<dim3(512, 2), dim3(256), 0, stream>>>(x, W_leaf, b_leaf, hA, cA);

    const float* hin = hA; const float* cin = cA;
    float* ho = hB; float* co = cB;
    int M = 16384;
    for (int lev = 1; lev <= 12; ++lev) {
        float* of = (lev == 12) ? out : nullptr;
        dim3 grid((M + BM - 1) / BM, 4);
        level_kernel<<<grid, dim3(256), 0, stream>>>(hin, cin, ho, co, Wcat, bcat, M, of);
        const float* nh = hin; const float* nc = cin;
        hin = ho; cin = co;
        ho = (float*)nh; co = (float*)nc;   // ping-pong
        M >>= 1;
    }
}

// Round 2
// 630.688 us; speedup vs baseline: 1.6274x; 1.6274x over previous
//
#include <hip/hip_runtime.h>
#include <hip/hip_bf16.h>
#include <math.h>

// TreeLSTM bf16-MFMA version. B=8, L=4096, D=300, H=128, 12 levels.
//   Leaf GEMM [32768,256,320] + levels 1-5 GEMM [M,640,256] on matrix cores
//   (fp32 accumulate, gates in fp32 workspace, separate LSTM epilogue).
//   c stays fp32 end-to-end; h stored bf16 (it feeds the next GEMM anyway).
//   Levels 6-12 (M<=512): latency-bound fp32 VALU kernel (fused epilogue).

typedef __attribute__((ext_vector_type(8))) short bfrag8;   // 8 bf16 = 4 VGPRs
typedef __attribute__((ext_vector_type(4))) float f32x4;

__device__ __forceinline__ float sigf(float x) { return 1.0f / (1.0f + __expf(-x)); }
__device__ __forceinline__ short f2bf(float f) {
    __hip_bfloat16 h = __float2bfloat16(f);
    return *reinterpret_cast<short*>(&h);
}
__device__ __forceinline__ float bf2f(short s) {
    unsigned int u = ((unsigned int)(unsigned short)s) << 16;
    float f; __builtin_memcpy(&f, &u, 4); return f;
}

// ---------------- build weight layouts (runs once, tiny) ----------------
// WcatT bf16 [640][256]  : WcatT[n][k] = (k<128 ? W_l[k][n] : W_r[k-128][n])      (gates GEMM B, k-major)
// WleafT bf16 [256][320] : WleafT[n][k] = k<300 ? W_leaf[k][n] : 0                (leaf GEMM B, k-major)
// WcatI fp32 [256][640]  : gate-interleaved for the fp32 tail kernel
// bcatI fp32 [640]       : bcatI[h*5+g] = b[g*128+h]
__global__ __launch_bounds__(256) void reorder_kernel(
    const float* __restrict__ W_l, const float* __restrict__ W_r,
    const float* __restrict__ b, const float* __restrict__ W_leaf,
    short* __restrict__ WcatT, short* __restrict__ WleafT,
    float* __restrict__ WcatI, float* __restrict__ bcatI)
{
    int idx = blockIdx.x * 256 + threadIdx.x;
    if (idx < 163840) {                       // WcatT
        int n = idx >> 8, k = idx & 255;
        float v = (k < 128) ? W_l[k * 640 + n] : W_r[(k - 128) * 640 + n];
        WcatT[idx] = f2bf(v);
        return;
    }
    idx -= 163840;
    if (idx < 81920) {                        // WleafT
        int n = idx / 320, k = idx - n * 320;
        WleafT[idx] = (k < 300) ? f2bf(W_leaf[k * 256 + n]) : (short)0;
        return;
    }
    idx -= 81920;
    if (idx < 163840) {                       // WcatI (fp32, gate-interleaved)
        int k = idx / 640, j = idx - k * 640;
        int h = j / 5, g = j - h * 5;
        int src = g * 128 + h;
        WcatI[idx] = (k < 128) ? W_l[k * 640 + src] : W_r[(k - 128) * 640 + src];
        return;
    }
    idx -= 163840;
    if (idx < 640) {                          // bcatI
        int h = idx / 5, g = idx - h * 5;
        bcatI[idx] = b[g * 128 + h];
    }
}

// ---------------- bf16 MFMA GEMM ----------------
// C[M][N] fp32 = A[M][K]bf16 @ B(k-major: [N][K])bf16.   M%128==0, N%128==0, K%64==0.
// If A==nullptr: A is Afp fp32 [M][ldAf] with zero-padding for k>=kvalid (leaf path).
// Block 256 thr = 4 waves; block tile 128x128; wave tile 64x64 = 4x4 mfma_16x16x32.
// LDS [128][64] bf16 per operand, XOR-swizzled 16B chunks: chunk c of row m at slot c^(m&7).
__global__ __launch_bounds__(256) void gemm_bf16_mfma(
    const short* __restrict__ A, const float* __restrict__ Afp, int ldAf, int kvalid,
    const short* __restrict__ B,
    float* __restrict__ C, int N, int K)
{
    __shared__ short Als[128 * 64];
    __shared__ short Bls[128 * 64];
    const int tid  = threadIdx.x;
    const int w    = tid >> 6, lane = tid & 63;
    const int quad = lane >> 4, l16 = lane & 15;
    const int mBlk = blockIdx.x * 128, nBlk = blockIdx.y * 128;
    const int waveM = (w >> 1) * 64, waveN = (w & 1) * 64;

    f32x4 acc[4][4] = {};

    const int lrow = lane >> 3;     // 0..7 within an 8-row segment
    const int lslot = lane & 7;     // 16B slot within a row

    for (int k0 = 0; k0 < K; k0 += 64) {
        // ---- stage B: global_load_lds, 16B/lane, 4 segs/wave ----
        #pragma unroll
        for (int r = 0; r < 4; ++r) {
            int seg = r * 4 + w;
            int row = seg * 8 + lrow;
            int c   = lslot ^ (row & 7);
            const short* gp = B + (size_t)(nBlk + row) * K + k0 + c * 8;
            __builtin_amdgcn_global_load_lds(
                (const __attribute__((address_space(1))) void*)gp,
                (__attribute__((address_space(3))) void*)(Bls + seg * 512),
                16, 0, 0);
        }
        // ---- stage A ----
        if (A) {
            #pragma unroll
            for (int r = 0; r < 4; ++r) {
                int seg = r * 4 + w;
                int row = seg * 8 + lrow;
                int c   = lslot ^ (row & 7);
                const short* gp = A + (size_t)(mBlk + row) * K + k0 + c * 8;
                __builtin_amdgcn_global_load_lds(
                    (const __attribute__((address_space(1))) void*)gp,
                    (__attribute__((address_space(3))) void*)(Als + seg * 512),
                    16, 0, 0);
            }
        } else {
            // fp32 -> bf16 convert staging (leaf A = x)
            for (int i = tid; i < 1024; i += 256) {
                int row = i >> 3, c = i & 7;
                union { bfrag8 v; short s[8]; } u;
                #pragma unroll
                for (int q = 0; q < 8; ++q) {
                    int kg = k0 + c * 8 + q;
                    u.s[q] = (kg < kvalid)
                           ? f2bf(Afp[(size_t)(mBlk + row) * ldAf + kg]) : (short)0;
                }
                int slot = c ^ (row & 7);
                *(bfrag8*)(Als + row * 64 + slot * 8) = u.v;
            }
        }
        __syncthreads();

        #pragma unroll
        for (int ks = 0; ks < 2; ++ks) {
            bfrag8 af[4], bfr[4];
            int cch = ks * 4 + quad;
            #pragma unroll
            for (int i = 0; i < 4; ++i) {
                int row = waveM + i * 16 + l16;
                af[i] = *(const bfrag8*)(Als + row * 64 + (cch ^ (row & 7)) * 8);
            }
            #pragma unroll
            for (int j = 0; j < 4; ++j) {
                int row = waveN + j * 16 + l16;
                bfr[j] = *(const bfrag8*)(Bls + row * 64 + (cch ^ (row & 7)) * 8);
            }
            #pragma unroll
            for (int i = 0; i < 4; ++i)
                #pragma unroll
                for (int j = 0; j < 4; ++j)
                    acc[i][j] = __builtin_amdgcn_mfma_f32_16x16x32_bf16(
                                    af[i], bfr[j], acc[i][j], 0, 0, 0);
        }
        __syncthreads();
    }

    // epilogue: C/D layout col=lane&15, row=quad*4+reg
    #pragma unroll
    for (int i = 0; i < 4; ++i) {
        int row0 = mBlk + waveM + i * 16 + quad * 4;
        #pragma unroll
        for (int j = 0; j < 4; ++j) {
            int col = nBlk + waveN + j * 16 + l16;
            #pragma unroll
            for (int rg = 0; rg < 4; ++rg)
                C[(size_t)(row0 + rg) * N + col] = acc[i][j][rg];
        }
    }
}

// ---------------- leaf post: split hc, add bias, h->bf16, c->fp32 ----------------
__global__ __launch_bounds__(256) void leafpost_kernel(
    const float* __restrict__ gates, const float* __restrict__ bleaf,
    short* __restrict__ h, float* __restrict__ c)
{
    int idx = blockIdx.x * 256 + threadIdx.x;   // 32768*128 exactly
    int row = idx >> 7, hh = idx & 127;
    h[idx] = f2bf(gates[(size_t)row * 256 + hh] + bleaf[hh]);
    c[idx] = gates[(size_t)row * 256 + 128 + hh] + bleaf[128 + hh];
}

// ---------------- LSTM epilogue for MFMA levels ----------------
// gates [M][640] plain layout (i,fl,fr,o,g strips of 128), cprev fp32 [2M][128].
__global__ __launch_bounds__(256) void lstm_epi_kernel(
    const float* __restrict__ gates, const float* __restrict__ b,
    const float* __restrict__ cprev,
    short* __restrict__ hout, float* __restrict__ cout, int M)
{
    int idx = blockIdx.x * 256 + threadIdx.x;
    if (idx >= M * 128) return;
    int row = idx >> 7, h = idx & 127;
    const float* g = gates + (size_t)row * 640;
    float gi  = g[h]       + b[h];
    float gfl = g[128 + h] + b[128 + h];
    float gfr = g[256 + h] + b[256 + h];
    float go  = g[384 + h] + b[384 + h];
    float gg  = g[512 + h] + b[512 + h];
    float cl  = cprev[(size_t)(2 * row) * 128 + h];
    float cr  = cprev[(size_t)(2 * row + 1) * 128 + h];
    float cn  = sigf(gfl) * cl + sigf(gfr) * cr + sigf(gi) * tanhf(gg);
    float hn  = sigf(go) * tanhf(cn);
    hout[idx] = f2bf(hn);
    cout[idx] = cn;
}

// ---------------- fp32 tail levels (M<=512, latency-bound) ----------------
#define KC 16
#define BM 64
#define AT_STRIDE 68
__global__ __launch_bounds__(256) void level_tail_kernel(
    const short* __restrict__ hprev, const float* __restrict__ cprev,
    short* __restrict__ hout, float* __restrict__ cout,
    const float* __restrict__ WcatI, const float* __restrict__ bcatI,
    int M, float* __restrict__ out_final)
{
    __shared__ float At[KC][AT_STRIDE];
    __shared__ float Bs[KC][160];
    const int tid = threadIdx.x;
    const int r0 = blockIdx.x * BM;
    const int j0 = blockIdx.y * 160;
    const int rg = tid >> 5, cg = tid & 31;
    const int hidx = blockIdx.y * 32 + cg;

    float binit[5];
    #pragma unroll
    for (int g = 0; g < 5; ++g) binit[g] = bcatI[hidx * 5 + g];
    float acc[8][5];
    #pragma unroll
    for (int r = 0; r < 8; ++r)
        #pragma unroll
        for (int g = 0; g < 5; ++g) acc[r][g] = binit[g];

    for (int k0 = 0; k0 < 256; k0 += KC) {
        #pragma unroll
        for (int i = tid; i < BM * KC; i += 256) {
            int m = i >> 4, kk = i & 15;
            At[kk][m] = bf2f(hprev[(size_t)(r0 + m) * 256 + k0 + kk]);
        }
        #pragma unroll
        for (int i = tid; i < KC * 160; i += 256) {
            int kk = i / 160, c = i - kk * 160;
            Bs[kk][c] = WcatI[(size_t)(k0 + kk) * 640 + j0 + c];
        }
        __syncthreads();
        #pragma unroll
        for (int kk = 0; kk < KC; ++kk) {
            float a[8], bv[5];
            #pragma unroll
            for (int r = 0; r < 8; ++r) a[r] = At[kk][rg * 8 + r];
            #pragma unroll
            for (int g = 0; g < 5; ++g) bv[g] = Bs[kk][cg * 5 + g];
            #pragma unroll
            for (int r = 0; r < 8; ++r)
                #pragma unroll
                for (int g = 0; g < 5; ++g) acc[r][g] += a[r] * bv[g];
        }
        __syncthreads();
    }
    #pragma unroll
    for (int r = 0; r < 8; ++r) {
        int row = r0 + rg * 8 + r;
        if (row < M) {
            float gi = acc[r][0], gfl = acc[r][1], gfr = acc[r][2];
            float go = acc[r][3], gg = acc[r][4];
            float cl = cprev[(size_t)(2 * row) * 128 + hidx];
            float cr = cprev[(size_t)(2 * row + 1) * 128 + hidx];
            float cn = sigf(gfl) * cl + sigf(gfr) * cr + sigf(gi) * tanhf(gg);
            float hn = sigf(go) * tanhf(cn);
            if (out_final) {
                out_final[(size_t)row * 128 + hidx] = hn;
            } else {
                hout[(size_t)row * 128 + hidx] = f2bf(hn);
                cout[(size_t)row * 128 + hidx] = cn;
            }
        }
    }
}

extern "C" void kernel_launch(void* const* d_in, const int* in_sizes, int n_in,
                              void* d_out, int out_size, void* d_ws, size_t ws_size,
                              hipStream_t stream)
{
    const float* x      = (const float*)d_in[0];
    const float* W_leaf = (const float*)d_in[1];
    const float* b_leaf = (const float*)d_in[2];
    const float* W_l    = (const float*)d_in[3];
    const float* W_r    = (const float*)d_in[4];
    const float* b      = (const float*)d_in[5];
    float* out = (float*)d_out;

    // workspace layout (~81 MB)
    char* p = (char*)d_ws;
    float* gates  = (float*)p; p += (size_t)16384 * 640 * 4;   // 41.94 MB (holds leaf gates too)
    short* h0     = (short*)p; p += (size_t)32768 * 128 * 2;   //  8.39 MB
    short* h1     = (short*)p; p += (size_t)16384 * 128 * 2;   //  4.19 MB
    float* c0     = (float*)p; p += (size_t)32768 * 128 * 4;   // 16.78 MB
    float* c1     = (float*)p; p += (size_t)16384 * 128 * 4;   //  8.39 MB
    short* WcatT  = (short*)p; p += (size_t)640 * 256 * 2;
    short* WleafT = (short*)p; p += (size_t)256 * 320 * 2;
    float* WcatI  = (float*)p; p += (size_t)256 * 640 * 4;
    float* bcatI  = (float*)p; p += 640 * 4;

    int totalR = 163840 + 81920 + 163840 + 640;
    reorder_kernel<<<(totalR + 255) / 256, 256, 0, stream>>>(
        W_l, W_r, b, W_leaf, WcatT, WleafT, WcatI, bcatI);

    // leaf: [32768,300]@[300,256] via MFMA (K padded to 320, fp32-convert staging)
    gemm_bf16_mfma<<<dim3(256, 2), 256, 0, stream>>>(
        nullptr, x, 300, 300, WleafT, gates, 256, 320);
    leafpost_kernel<<<(32768 * 128) / 256, 256, 0, stream>>>(gates, b_leaf, h0, c0);

    const short* hin = h0;
    const float* cin = c0;
    int M = 16384;
    for (int lev = 1; lev <= 12; ++lev) {
        short* ho = (lev & 1) ? h1 : h0;
        float* co = (lev & 1) ? c1 : c0;
        if (M >= 1024) {
            gemm_bf16_mfma<<<dim3(M / 128, 5), 256, 0, stream>>>(
                hin, nullptr, 0, 0, WcatT, gates, 640, 256);
            lstm_epi_kernel<<<(M * 128) / 256, 256, 0, stream>>>(
                gates, b, cin, ho, co, M);
        } else {
            float* of = (lev == 12) ? out : nullptr;
            level_tail_kernel<<<dim3((M + 63) / 64, 4), 256, 0, stream>>>(
                hin, cin, ho, co, WcatI, bcatI, M, of);
        }
        hin = ho; cin = co;
        M >>= 1;
    }
}

// Round 3
// 432.734 us; speedup vs baseline: 2.3719x; 1.4574x over previous
//
#include <hip/hip_runtime.h>
#include <hip/hip_bf16.h>
#include <math.h>

// TreeLSTM, B=8, L=4096, D=300, H=128, 12 levels. Round 3:
//   - fused_level_kernel: gates GEMM (bf16 MFMA) + LSTM epilogue in ONE kernel,
//     used for ALL 12 levels. Block = 64 rows x 640 cols; wave w owns h-range
//     [32w,32w+32) across all 5 gates, so the 5 gate logits of each (row,h)
//     land in one lane -> epilogue fully in-register, gates never hit memory.
//   - leaf unchanged from round 2 (MFMA gemm w/ fp32->bf16 convert staging).
//   - tail VALU kernel deleted (7 x 84us latency-bound launches).

typedef __attribute__((ext_vector_type(8))) short bfrag8;   // 8 bf16 = 4 VGPRs
typedef __attribute__((ext_vector_type(4))) float f32x4;

__device__ __forceinline__ float sigf(float x) { return 1.0f / (1.0f + __expf(-x)); }
__device__ __forceinline__ short f2bf(float f) {
    __hip_bfloat16 h = __float2bfloat16(f);
    return *reinterpret_cast<short*>(&h);
}

// ---------------- build weight layouts (runs once, tiny) ----------------
// WcatT bf16 [640][256]  : WcatT[n][k] = (k<128 ? W_l[k][n] : W_r[k-128][n]), n = g*128+h
// WleafT bf16 [256][320] : WleafT[n][k] = k<300 ? W_leaf[k][n] : 0
__global__ __launch_bounds__(256) void reorder_kernel(
    const float* __restrict__ W_l, const float* __restrict__ W_r,
    const float* __restrict__ W_leaf,
    short* __restrict__ WcatT, short* __restrict__ WleafT)
{
    int idx = blockIdx.x * 256 + threadIdx.x;
    if (idx < 163840) {                       // WcatT
        int n = idx >> 8, k = idx & 255;
        float v = (k < 128) ? W_l[k * 640 + n] : W_r[(k - 128) * 640 + n];
        WcatT[idx] = f2bf(v);
        return;
    }
    idx -= 163840;
    if (idx < 81920) {                        // WleafT
        int n = idx / 320, k = idx - n * 320;
        WleafT[idx] = (k < 300) ? f2bf(W_leaf[k * 256 + n]) : (short)0;
    }
}

// ---------------- leaf GEMM (round-2 proven): [32768,300]@[300,256] ----------------
__global__ __launch_bounds__(256) void gemm_leaf_mfma(
    const float* __restrict__ Afp, int ldAf, int kvalid,
    const short* __restrict__ B,
    float* __restrict__ C, int N, int K)
{
    __shared__ short Als[128 * 64];
    __shared__ short Bls[128 * 64];
    const int tid  = threadIdx.x;
    const int w    = tid >> 6, lane = tid & 63;
    const int quad = lane >> 4, l16 = lane & 15;
    const int mBlk = blockIdx.x * 128, nBlk = blockIdx.y * 128;
    const int waveM = (w >> 1) * 64, waveN = (w & 1) * 64;

    f32x4 acc[4][4] = {};
    const int lrow = lane >> 3;
    const int lslot = lane & 7;

    for (int k0 = 0; k0 < K; k0 += 64) {
        // stage B via global_load_lds (16B), swizzle on global chunk index
        #pragma unroll
        for (int r = 0; r < 4; ++r) {
            int seg = r * 4 + w;
            int row = seg * 8 + lrow;
            int c   = lslot ^ (row & 7);
            const short* gp = B + (size_t)(nBlk + row) * K + k0 + c * 8;
            __builtin_amdgcn_global_load_lds(
                (const __attribute__((address_space(1))) void*)gp,
                (__attribute__((address_space(3))) void*)(Bls + seg * 512),
                16, 0, 0);
        }
        // stage A: fp32 -> bf16 convert (x is fp32, K padded to 320)
        for (int i = tid; i < 1024; i += 256) {
            int row = i >> 3, c = i & 7;
            union { bfrag8 v; short s[8]; } u;
            #pragma unroll
            for (int q = 0; q < 8; ++q) {
                int kg = k0 + c * 8 + q;
                u.s[q] = (kg < kvalid)
                       ? f2bf(Afp[(size_t)(mBlk + row) * ldAf + kg]) : (short)0;
            }
            int slot = c ^ (row & 7);
            *(bfrag8*)(Als + row * 64 + slot * 8) = u.v;
        }
        __syncthreads();

        #pragma unroll
        for (int ks = 0; ks < 2; ++ks) {
            bfrag8 af[4], bfr[4];
            int cch = ks * 4 + quad;
            #pragma unroll
            for (int i = 0; i < 4; ++i) {
                int row = waveM + i * 16 + l16;
                af[i] = *(const bfrag8*)(Als + row * 64 + (cch ^ (row & 7)) * 8);
            }
            #pragma unroll
            for (int j = 0; j < 4; ++j) {
                int row = waveN + j * 16 + l16;
                bfr[j] = *(const bfrag8*)(Bls + row * 64 + (cch ^ (row & 7)) * 8);
            }
            #pragma unroll
            for (int i = 0; i < 4; ++i)
                #pragma unroll
                for (int j = 0; j < 4; ++j)
                    acc[i][j] = __builtin_amdgcn_mfma_f32_16x16x32_bf16(
                                    af[i], bfr[j], acc[i][j], 0, 0, 0);
        }
        __syncthreads();
    }

    #pragma unroll
    for (int i = 0; i < 4; ++i) {
        int row0 = mBlk + waveM + i * 16 + quad * 4;
        #pragma unroll
        for (int j = 0; j < 4; ++j) {
            int col = nBlk + waveN + j * 16 + l16;
            #pragma unroll
            for (int rg = 0; rg < 4; ++rg)
                C[(size_t)(row0 + rg) * N + col] = acc[i][j][rg];
        }
    }
}

// ---------------- leaf post: split hc, add bias, h->bf16, c->fp32 ----------------
__global__ __launch_bounds__(256) void leafpost_kernel(
    const float* __restrict__ gates, const float* __restrict__ bleaf,
    short* __restrict__ h, float* __restrict__ c)
{
    int idx = blockIdx.x * 256 + threadIdx.x;   // 32768*128 exactly
    int row = idx >> 7, hh = idx & 127;
    h[idx] = f2bf(gates[(size_t)row * 256 + hh] + bleaf[hh]);
    c[idx] = gates[(size_t)row * 256 + 128 + hh] + bleaf[128 + hh];
}

// ---------------- fused level: gates GEMM + LSTM epilogue ----------------
// A = hprev viewed [M][256] bf16 (children concatenated), B = WcatT [640][256].
// Block: 64 rows x 640 cols. Wave w: all 64 rows x cols {g*128 + w*32 + [0,32)}.
// LDS pair-swizzle: 64B rows, pair P = row>>1 holds 8 chunks of 16B; global
// chunk c of pair P stored at slot c ^ (P&7)  -> 2-way (free) bank aliasing.
__global__ __launch_bounds__(256) void fused_level_kernel(
    const short* __restrict__ hprev,   // [M][256] bf16
    const float* __restrict__ cprev,   // [2M][128] fp32
    const short* __restrict__ Wcat,    // [640][256] bf16
    const float* __restrict__ bias,    // [640] fp32 (plain: g*128+h)
    short* __restrict__ hout,          // [M][128] bf16
    float* __restrict__ cout,          // [M][128] fp32
    int M, float* __restrict__ out_final)
{
    __shared__ short Als[64 * 32];     // 4 KB
    __shared__ short Bls[640 * 32];    // 40 KB
    const int tid  = threadIdx.x;
    const int w    = tid >> 6, lane = tid & 63;
    const int quad = lane >> 4, l16 = lane & 15;
    const int mBlk = blockIdx.x * 64;

    f32x4 acc[4][10] = {};             // [m-tile][g*2+half]

    // staging lane geometry (per 16-row round, 1 KB)
    const int pr = lane >> 3;          // pair within round 0..7
    const int sl = lane & 7;           // slot
    const int sw = sl ^ pr;            // global chunk index to fetch
    const int rowInRound = 2 * pr + (sw >> 2);
    const int chunkOff   = (sw & 3) * 16;   // bytes

    for (int k0 = 0; k0 < 256; k0 += 32) {
        // ---- stage A: 1 round/wave (16 rows x 32k = 1 KB) ----
        {
            int gr = mBlk + w * 16 + rowInRound;
            if (gr >= M) gr = 0;                      // clamped rows: garbage, stores guarded
            const char* gp = (const char*)hprev + (size_t)gr * 512 + k0 * 2 + chunkOff;
            __builtin_amdgcn_global_load_lds(
                (const __attribute__((address_space(1))) void*)gp,
                (__attribute__((address_space(3))) void*)((char*)Als + w * 1024),
                16, 0, 0);
        }
        // ---- stage B: 10 rounds/wave (160 rows) ----
        #pragma unroll
        for (int q = 0; q < 10; ++q) {
            int round = w * 10 + q;
            int n = round * 16 + rowInRound;
            const char* gp = (const char*)Wcat + (size_t)n * 512 + k0 * 2 + chunkOff;
            __builtin_amdgcn_global_load_lds(
                (const __attribute__((address_space(1))) void*)gp,
                (__attribute__((address_space(3))) void*)((char*)Bls + round * 1024),
                16, 0, 0);
        }
        __syncthreads();

        // ---- fragments + MFMA ----
        bfrag8 af[4];
        #pragma unroll
        for (int mt = 0; mt < 4; ++mt) {
            int m = mt * 16 + l16;
            int P = m >> 1, c = ((m & 1) << 2) | quad;
            af[mt] = *(const bfrag8*)((const char*)Als + P * 128 + ((c ^ (P & 7)) << 4));
        }
        #pragma unroll
        for (int g = 0; g < 5; ++g) {
            #pragma unroll
            for (int half = 0; half < 2; ++half) {
                int n = g * 128 + w * 32 + half * 16 + l16;
                int P = n >> 1, c = ((n & 1) << 2) | quad;
                bfrag8 bf = *(const bfrag8*)((const char*)Bls + P * 128 + ((c ^ (P & 7)) << 4));
                #pragma unroll
                for (int mt = 0; mt < 4; ++mt)
                    acc[mt][g * 2 + half] = __builtin_amdgcn_mfma_f32_16x16x32_bf16(
                                                af[mt], bf, acc[mt][g * 2 + half], 0, 0, 0);
            }
        }
        __syncthreads();
    }

    // ---- fused LSTM epilogue: lane holds all 5 gates of (row,h) ----
    #pragma unroll
    for (int mt = 0; mt < 4; ++mt) {
        #pragma unroll
        for (int rg = 0; rg < 4; ++rg) {
            int row = mBlk + mt * 16 + quad * 4 + rg;
            if (row < M) {
                #pragma unroll
                for (int half = 0; half < 2; ++half) {
                    int h = w * 32 + half * 16 + l16;
                    float gi  = acc[mt][0 + half][rg] + bias[h];
                    float gfl = acc[mt][2 + half][rg] + bias[128 + h];
                    float gfr = acc[mt][4 + half][rg] + bias[256 + h];
                    float go  = acc[mt][6 + half][rg] + bias[384 + h];
                    float gg  = acc[mt][8 + half][rg] + bias[512 + h];
                    float cl  = cprev[(size_t)(2 * row) * 128 + h];
                    float cr  = cprev[(size_t)(2 * row + 1) * 128 + h];
                    float cn  = sigf(gfl) * cl + sigf(gfr) * cr + sigf(gi) * tanhf(gg);
                    float hn  = sigf(go) * tanhf(cn);
                    if (out_final) {
                        out_final[(size_t)row * 128 + h] = hn;
                    } else {
                        hout[(size_t)row * 128 + h] = f2bf(hn);
                        cout[(size_t)row * 128 + h] = cn;
                    }
                }
            }
        }
    }
}

extern "C" void kernel_launch(void* const* d_in, const int* in_sizes, int n_in,
                              void* d_out, int out_size, void* d_ws, size_t ws_size,
                              hipStream_t stream)
{
    const float* x      = (const float*)d_in[0];
    const float* W_leaf = (const float*)d_in[1];
    const float* b_leaf = (const float*)d_in[2];
    const float* W_l    = (const float*)d_in[3];
    const float* W_r    = (const float*)d_in[4];
    const float* b      = (const float*)d_in[5];
    float* out = (float*)d_out;

    // workspace (~72 MB)
    char* p = (char*)d_ws;
    float* gates  = (float*)p; p += (size_t)32768 * 256 * 4;   // 33.55 MB (leaf only)
    short* h0     = (short*)p; p += (size_t)32768 * 128 * 2;   //  8.39 MB
    short* h1     = (short*)p; p += (size_t)16384 * 128 * 2;   //  4.19 MB
    float* c0     = (float*)p; p += (size_t)32768 * 128 * 4;   // 16.78 MB
    float* c1     = (float*)p; p += (size_t)16384 * 128 * 4;   //  8.39 MB
    short* WcatT  = (short*)p; p += (size_t)640 * 256 * 2;
    short* WleafT = (short*)p; p += (size_t)256 * 320 * 2;

    reorder_kernel<<<(163840 + 81920 + 255) / 256, 256, 0, stream>>>(
        W_l, W_r, W_leaf, WcatT, WleafT);

    gemm_leaf_mfma<<<dim3(256, 2), 256, 0, stream>>>(
        x, 300, 300, WleafT, gates, 256, 320);
    leafpost_kernel<<<(32768 * 128) / 256, 256, 0, stream>>>(gates, b_leaf, h0, c0);

    const short* hin = h0;
    const float* cin = c0;
    int M = 16384;
    for (int lev = 1; lev <= 12; ++lev) {
        short* ho = (lev & 1) ? h1 : h0;
        float* co = (lev & 1) ? c1 : c0;
        float* of = (lev == 12) ? out : nullptr;
        fused_level_kernel<<<dim3((M + 63) / 64), 256, 0, stream>>>(
            hin, cin, WcatT, b, ho, co, M, of);
        hin = ho; cin = co;
        M >>= 1;
    }
}